// Round 6
// baseline (82.787 us; speedup 1.0000x reference)
//
#include <hip/hip_runtime.h>
#include <hip/hip_bf16.h>
#include <math.h>

#define N_NODES 204800
#define B_GRAPHS 4096
#define DIM 128

typedef __attribute__((ext_vector_type(8))) short bf16x8;
typedef __attribute__((ext_vector_type(4))) float f32x4;

__device__ __forceinline__ float sigf(float x) {
    return 1.0f / (1.0f + __expf(-x));
}

// round-to-nearest-even fp32 -> bf16
__device__ __forceinline__ unsigned short bfrne(float x) {
    unsigned u = __float_as_uint(x);
    unsigned r = u + 0x7FFFu + ((u >> 16) & 1u);
    return (unsigned short)(r >> 16);
}

// ---------------------------------------------------------------------------
// Kernel 1, three independent jobs selected by blockIdx.x:
//   [0..512):    q[b] = U_feat[b]@W_user + b_user + feat[last[b]]@W_last
//   [512..576):  Wt_bf16[c][k] = bf16(W_key[k][c])
//   [576..2176): segment bounds scatter: bounds[b] = first node of graph b
// ---------------------------------------------------------------------------
__global__ __launch_bounds__(128) void qkernel(
    const float* __restrict__ feat, const float* __restrict__ U_feat,
    const float* __restrict__ W_user, const float* __restrict__ b_user,
    const float* __restrict__ W_last, const int* __restrict__ last_nodes,
    const float* __restrict__ W_key, unsigned short* __restrict__ Wt,
    const int* __restrict__ seg, int* __restrict__ bounds,
    float* __restrict__ q) {
  if (blockIdx.x >= 576) {
    int n = (blockIdx.x - 576) * 128 + threadIdx.x;
    int sc = seg[n];
    int sp = (n == 0) ? -1 : seg[n - 1];
    for (int b = sp + 1; b <= sc; ++b) bounds[b] = (b == 0) ? 0 : n;
    if (n == N_NODES - 1)
      for (int b = sc + 1; b <= B_GRAPHS; ++b) bounds[b] = N_NODES;
    return;
  }
  if (blockIdx.x >= 512) {
    int b = blockIdx.x - 512;  // 0..63
#pragma unroll
    for (int j = 0; j < 2; ++j) {
      int o = b * 256 + j * 128 + threadIdx.x;  // halfword index in Wt
      int c = o >> 7, k = o & 127;
      Wt[o] = bfrne(W_key[k * DIM + c]);
    }
    return;
  }
  __shared__ float sU[8][DIM];
  __shared__ float sL[8][DIM];
  const int d = threadIdx.x;
  const int g0 = blockIdx.x * 8;
  for (int g = 0; g < 8; ++g) {
    sU[g][d] = U_feat[(g0 + g) * DIM + d];
    int ln = last_nodes[g0 + g];
    sL[g][d] = feat[ln * DIM + d];
  }
  __syncthreads();
  float acc[8];
#pragma unroll
  for (int g = 0; g < 8; ++g) acc[g] = 0.0f;

  for (int kk = 0; kk < 32; ++kk) {
    float wu[4], wl[4];
#pragma unroll
    for (int j = 0; j < 4; ++j) {
      wu[j] = W_user[(kk * 4 + j) * DIM + d];
      wl[j] = W_last[(kk * 4 + j) * DIM + d];
    }
#pragma unroll
    for (int g = 0; g < 8; ++g) {
      float4 u4 = reinterpret_cast<const float4*>(sU[g])[kk];
      float4 l4 = reinterpret_cast<const float4*>(sL[g])[kk];
      acc[g] += u4.x * wu[0] + u4.y * wu[1] + u4.z * wu[2] + u4.w * wu[3];
      acc[g] += l4.x * wl[0] + l4.y * wl[1] + l4.z * wl[2] + l4.w * wl[3];
    }
  }
  float bu = b_user[d];
  for (int g = 0; g < 8; ++g) q[(g0 + g) * DIM + d] = acc[g] + bu;
}

// ---------------------------------------------------------------------------
// ekernel helper: one 128-node chunk (per wave: 2 tiles of 16 nodes).
// Swapped-operand MFMA: D[keycol = 4*lh + reg][node = lr].
// ---------------------------------------------------------------------------
__device__ __forceinline__ void compute_chunk(
    const unsigned short* sW, const float* sWe, const bf16x8 (&af)[2][4],
    const float4 (&qv)[2][8], const float (&lc)[2], int nodebase, int lr,
    int lh, float* __restrict__ e) {
  float p[2] = {0.0f, 0.0f};
#pragma unroll
  for (int c = 0; c < 8; ++c) {
    const int row = c * 16 + lr;
    bf16x8 wf[4];
#pragma unroll
    for (int ks = 0; ks < 4; ++ks)
      wf[ks] = *reinterpret_cast<const bf16x8*>(
          &sW[row * DIM + ((ks * 32 + lh * 8) ^ ((row & 7) << 3))]);
    float4 we = *reinterpret_cast<const float4*>(&sWe[c * 16 + lh * 4]);

    f32x4 a0 = f32x4{0.f, 0.f, 0.f, 0.f};
    f32x4 a1 = f32x4{0.f, 0.f, 0.f, 0.f};
#pragma unroll
    for (int ks = 0; ks < 4; ++ks) {
      a0 = __builtin_amdgcn_mfma_f32_16x16x32_bf16(wf[ks], af[0][ks], a0, 0, 0, 0);
      a1 = __builtin_amdgcn_mfma_f32_16x16x32_bf16(wf[ks], af[1][ks], a1, 0, 0, 0);
    }
    float4 q0 = qv[0][c], q1 = qv[1][c];
    p[0] += we.x * sigf(a0[0] + q0.x) + we.y * sigf(a0[1] + q0.y) +
            we.z * sigf(a0[2] + q0.z) + we.w * sigf(a0[3] + q0.w);
    p[1] += we.x * sigf(a1[0] + q1.x) + we.y * sigf(a1[1] + q1.y) +
            we.z * sigf(a1[2] + q1.z) + we.w * sigf(a1[3] + q1.w);
  }
#pragma unroll
  for (int t = 0; t < 2; ++t) {
    float v = p[t];
    v += __shfl_xor(v, 16, 64);
    v += __shfl_xor(v, 32, 64);
    if (lh == 0) e[nodebase + t * 16 + lr] = v + __logf(lc[t]);
  }
}

__device__ __forceinline__ void load_feat(const float* __restrict__ feat,
                                          int node0, int lh, int lr,
                                          float4 (&fv)[2][4][2]) {
#pragma unroll
  for (int t = 0; t < 2; ++t) {
    const float* rp = feat + (size_t)(node0 + t * 16 + lr) * DIM + lh * 8;
#pragma unroll
    for (int ks = 0; ks < 4; ++ks) {
      fv[t][ks][0] = *reinterpret_cast<const float4*>(rp + ks * 32);
      fv[t][ks][1] = *reinterpret_cast<const float4*>(rp + ks * 32 + 4);
    }
  }
}

__device__ __forceinline__ void cvt_feat(const float4 (&fv)[2][4][2],
                                         bf16x8 (&af)[2][4]) {
#pragma unroll
  for (int t = 0; t < 2; ++t)
#pragma unroll
    for (int ks = 0; ks < 4; ++ks) {
      union { bf16x8 v; unsigned short u[8]; } a;
      a.u[0] = bfrne(fv[t][ks][0].x); a.u[1] = bfrne(fv[t][ks][0].y);
      a.u[2] = bfrne(fv[t][ks][0].z); a.u[3] = bfrne(fv[t][ks][0].w);
      a.u[4] = bfrne(fv[t][ks][1].x); a.u[5] = bfrne(fv[t][ks][1].y);
      a.u[6] = bfrne(fv[t][ks][1].z); a.u[7] = bfrne(fv[t][ks][1].w);
      af[t][ks] = a.v;
    }
}

// ---------------------------------------------------------------------------
// Kernel 2: e[n] = sigmoid(q[seg[n]] + (feat[n] @ W_key)) . w_e + log(cnt[n])
// 800 blocks x 256 thr, 256 nodes/block in 2 chunks of 128. W + w_e staged in
// LDS once per block. Pipeline: seg/cnt for both chunks + chunk0 feat/q issued
// before the staging barrier; chunk1 feat issued before chunk0's c-loop (its
// latency hides under MFMA+sigmoid); only chunk1's q-gather (~L2 latency) is
// exposed. No min-waves cap: ~200 VGPR -> 8 waves/CU, deep per-wave ILP.
// ---------------------------------------------------------------------------
__global__ __launch_bounds__(256) void ekernel(
    const float* __restrict__ feat, const unsigned short* __restrict__ Wt,
    const float* __restrict__ w_e, const float* __restrict__ cnt,
    const int* __restrict__ seg, const float* __restrict__ q,
    float* __restrict__ e) {
  __shared__ unsigned short sW[128 * DIM];
  __shared__ float sWe[DIM];
  const int tid = threadIdx.x;
  const int base0 = blockIdx.x * 256;
  const int l = tid & 63, w = tid >> 6;
  const int lr = l & 15, lh = l >> 4;

  // ---- seg + cnt for BOTH chunks, issued first (hide under W staging)
  int sg[2][2];
  float lc[2][2];
#pragma unroll
  for (int ch = 0; ch < 2; ++ch)
#pragma unroll
    for (int t = 0; t < 2; ++t) {
      int node = base0 + ch * 128 + w * 32 + t * 16 + lr;
      sg[ch][t] = seg[node];
      lc[ch][t] = cnt[node];
    }

  // ---- chunk0 feat loads
  float4 fv[2][4][2];
  load_feat(feat, base0 + w * 32, lh, lr, fv);

  // ---- chunk0 q gather (addresses ready as soon as sg lands)
  const float4* q4p = reinterpret_cast<const float4*>(q);
  float4 qv[2][8];
#pragma unroll
  for (int t = 0; t < 2; ++t)
#pragma unroll
    for (int c = 0; c < 8; ++c)
      qv[t][c] = q4p[(size_t)sg[0][t] * 32 + c * 4 + lh];

  // ---- stage W + w_e into LDS
  const uint4* Wt4 = reinterpret_cast<const uint4*>(Wt);
#pragma unroll
  for (int i = 0; i < 8; ++i) {
    int hw = i * 2048 + tid * 8;
    int row = hw >> 7, k0 = hw & 127;
    uint4 wv = Wt4[i * 256 + tid];
    *reinterpret_cast<uint4*>(&sW[row * DIM + (k0 ^ ((row & 7) << 3))]) = wv;
  }
  if (tid < 32)
    reinterpret_cast<float4*>(sWe)[tid] =
        reinterpret_cast<const float4*>(w_e)[tid];

  // ---- cvt chunk0 fragments
  bf16x8 af[2][4];
  cvt_feat(fv, af);

  __syncthreads();

  // ---- prefetch chunk1 feat (latency hides under chunk0 c-loop)
  float4 fv2[2][4][2];
  load_feat(feat, base0 + 128 + w * 32, lh, lr, fv2);

  // ---- chunk0 compute
  compute_chunk(sW, sWe, af, qv, lc[0], base0 + w * 32, lr, lh, e);

  // ---- chunk1: q gather, cvt, compute
#pragma unroll
  for (int t = 0; t < 2; ++t)
#pragma unroll
    for (int c = 0; c < 8; ++c)
      qv[t][c] = q4p[(size_t)sg[1][t] * 32 + c * 4 + lh];
  cvt_feat(fv2, af);
  compute_chunk(sW, sWe, af, qv, lc[1], base0 + 128 + w * 32, lr, lh, e);
}

// ---------------------------------------------------------------------------
// Kernel 3: per-graph segment softmax + weighted sum of feat_i.
// ---------------------------------------------------------------------------
__global__ __launch_bounds__(256) void skernel(
    const float* __restrict__ feat, const int* __restrict__ bounds,
    float* __restrict__ e, float* __restrict__ rst) {
  const int b = blockIdx.x;
  const int tid = threadIdx.x;
  const int s0 = bounds[b];
  const int s1 = bounds[b + 1];

  if (s1 <= s0) {
    if (tid < DIM) rst[b * DIM + tid] = 0.0f;
    return;
  }

  __shared__ float red[8];
  __shared__ float part[8 * DIM];
  const int wave = tid >> 6, lane = tid & 63;

  float lm = -3.0e38f;
  for (int i = s0 + tid; i < s1; i += 256) lm = fmaxf(lm, e[i]);
#pragma unroll
  for (int off = 32; off >= 1; off >>= 1) lm = fmaxf(lm, __shfl_xor(lm, off, 64));
  if (lane == 0) red[wave] = lm;
  __syncthreads();
  const float m = fmaxf(fmaxf(red[0], red[1]), fmaxf(red[2], red[3]));

  float ls = 0.0f;
  for (int i = s0 + tid; i < s1; i += 256) {
    float p = __expf(e[i] - m);
    e[i] = p;
    ls += p;
  }
#pragma unroll
  for (int off = 32; off >= 1; off >>= 1) ls += __shfl_xor(ls, off, 64);
  if (lane == 0) red[4 + wave] = ls;
  __syncthreads();
  const float inv = 1.0f / (red[4] + red[5] + red[6] + red[7]);

  const int c = tid & 31;
  const int h = tid >> 5;
  float4 acc = float4{0.f, 0.f, 0.f, 0.f};
  const float4* feat4 = reinterpret_cast<const float4*>(feat);
  for (int n = s0 + h; n < s1; n += 8) {
    float p = e[n];
    float4 f = feat4[n * 32 + c];
    acc.x += p * f.x;
    acc.y += p * f.y;
    acc.z += p * f.z;
    acc.w += p * f.w;
  }
  reinterpret_cast<float4*>(part)[h * 32 + c] = acc;
  __syncthreads();
  if (tid < DIM) {
    float tot = 0.0f;
#pragma unroll
    for (int hh = 0; hh < 8; ++hh) tot += part[hh * DIM + tid];
    rst[b * DIM + tid] = tot * inv;
  }
}

// ---------------------------------------------------------------------------
extern "C" void kernel_launch(void* const* d_in, const int* in_sizes, int n_in,
                              void* d_out, int out_size, void* d_ws,
                              size_t ws_size, hipStream_t stream) {
  const float* feat = (const float*)d_in[0];
  const float* U_feat = (const float*)d_in[1];
  const float* cnt = (const float*)d_in[2];
  const float* W_key = (const float*)d_in[3];
  const float* W_user = (const float*)d_in[4];
  const float* b_user = (const float*)d_in[5];
  const float* W_last = (const float*)d_in[6];
  const float* w_e = (const float*)d_in[7];
  const int* last_nodes = (const int*)d_in[8];
  const int* seg = (const int*)d_in[9];
  float* out = (float*)d_out;

  float* q = (float*)d_ws;                       // 4096*128 f32 (2 MB)
  float* e = q + B_GRAPHS * DIM;                 // 204800 f32 (0.82 MB)
  unsigned short* Wt = (unsigned short*)(e + N_NODES);   // 128*128 bf16 (32 KB)
  int* bounds = (int*)(Wt + DIM * DIM);          // 4097 ints

  qkernel<<<512 + 64 + N_NODES / 128, 128, 0, stream>>>(
      feat, U_feat, W_user, b_user, W_last, last_nodes, W_key, Wt, seg, bounds, q);
  ekernel<<<N_NODES / 256, 256, 0, stream>>>(feat, Wt, w_e, cnt, seg, q, e);
  skernel<<<B_GRAPHS, 256, 0, stream>>>(feat, bounds, e, out);
}

// Round 8
// 63.776 us; speedup vs baseline: 1.2981x; 1.2981x over previous
//
#include <hip/hip_runtime.h>
#include <hip/hip_bf16.h>
#include <math.h>

#define N_NODES 204800
#define B_GRAPHS 4096
#define DIM 128

typedef __attribute__((ext_vector_type(8))) short bf16x8;
typedef __attribute__((ext_vector_type(4))) float f32x4;

__device__ __forceinline__ float sigf(float x) {
    return 1.0f / (1.0f + __expf(-x));
}

// round-to-nearest-even fp32 -> bf16
__device__ __forceinline__ unsigned short bfrne(float x) {
    unsigned u = __float_as_uint(x);
    unsigned r = u + 0x7FFFu + ((u >> 16) & 1u);
    return (unsigned short)(r >> 16);
}

// ---------------------------------------------------------------------------
// Kernel 1, three independent jobs selected by blockIdx.x:
//   [0..512):    q[b] = U_feat[b]@W_user + b_user + feat[last[b]]@W_last
//   [512..576):  Wt_bf16[c][k] = bf16(W_key[k][c])
//   [576..2176): segment bounds scatter: bounds[b] = first node of graph b
// ---------------------------------------------------------------------------
__global__ __launch_bounds__(128) void qkernel(
    const float* __restrict__ feat, const float* __restrict__ U_feat,
    const float* __restrict__ W_user, const float* __restrict__ b_user,
    const float* __restrict__ W_last, const int* __restrict__ last_nodes,
    const float* __restrict__ W_key, unsigned short* __restrict__ Wt,
    const int* __restrict__ seg, int* __restrict__ bounds,
    float* __restrict__ q) {
  if (blockIdx.x >= 576) {
    int n = (blockIdx.x - 576) * 128 + threadIdx.x;
    int sc = seg[n];
    int sp = (n == 0) ? -1 : seg[n - 1];
    for (int b = sp + 1; b <= sc; ++b) bounds[b] = (b == 0) ? 0 : n;
    if (n == N_NODES - 1)
      for (int b = sc + 1; b <= B_GRAPHS; ++b) bounds[b] = N_NODES;
    return;
  }
  if (blockIdx.x >= 512) {
    int b = blockIdx.x - 512;  // 0..63
#pragma unroll
    for (int j = 0; j < 2; ++j) {
      int o = b * 256 + j * 128 + threadIdx.x;  // halfword index in Wt
      int c = o >> 7, k = o & 127;
      Wt[o] = bfrne(W_key[k * DIM + c]);
    }
    return;
  }
  __shared__ float sU[8][DIM];
  __shared__ float sL[8][DIM];
  const int d = threadIdx.x;
  const int g0 = blockIdx.x * 8;
  for (int g = 0; g < 8; ++g) {
    sU[g][d] = U_feat[(g0 + g) * DIM + d];
    int ln = last_nodes[g0 + g];
    sL[g][d] = feat[ln * DIM + d];
  }
  __syncthreads();
  float acc[8];
#pragma unroll
  for (int g = 0; g < 8; ++g) acc[g] = 0.0f;

  for (int kk = 0; kk < 32; ++kk) {
    float wu[4], wl[4];
#pragma unroll
    for (int j = 0; j < 4; ++j) {
      wu[j] = W_user[(kk * 4 + j) * DIM + d];
      wl[j] = W_last[(kk * 4 + j) * DIM + d];
    }
#pragma unroll
    for (int g = 0; g < 8; ++g) {
      float4 u4 = reinterpret_cast<const float4*>(sU[g])[kk];
      float4 l4 = reinterpret_cast<const float4*>(sL[g])[kk];
      acc[g] += u4.x * wu[0] + u4.y * wu[1] + u4.z * wu[2] + u4.w * wu[3];
      acc[g] += l4.x * wl[0] + l4.y * wl[1] + l4.z * wl[2] + l4.w * wl[3];
    }
  }
  float bu = b_user[d];
  for (int g = 0; g < 8; ++g) q[(g0 + g) * DIM + d] = acc[g] + bu;
}

// ---------------------------------------------------------------------------
// Kernel 2: e[n] = sigmoid(q[seg[n]] + (feat[n] @ W_key)) . w_e + log(cnt[n])
// 1600 blocks x 512 thr (8 waves), 128 nodes/block, ONE 16-node tile per wave.
// Per-thread live state ~100 VGPR -> __launch_bounds__(512,4) holds 128 VGPR,
// 4 waves/SIMD, no spills: the 8 feat float4 loads issue as one burst with a
// single vmcnt drain. W + w_e staged once per block in LDS (swizzled,
// R2-verified). Swapped-operand MFMA: D[keycol = c*16+4*lh+reg][node = lr].
// ---------------------------------------------------------------------------
__global__ __launch_bounds__(512, 4) void ekernel(
    const float* __restrict__ feat, const unsigned short* __restrict__ Wt,
    const float* __restrict__ w_e, const float* __restrict__ cnt,
    const int* __restrict__ seg, const float* __restrict__ q,
    float* __restrict__ e) {
  __shared__ unsigned short sW[128 * DIM];
  __shared__ float sWe[DIM];
  const int tid = threadIdx.x;
  const int base = blockIdx.x * 128;
  const int l = tid & 63, w = tid >> 6;     // 8 waves
  const int lr = l & 15, lh = l >> 4;
  const int node = base + w * 16 + lr;      // this lane's node (lh-replicated)

  // ---- seg + cnt first (q addresses depend on seg)
  const int sg = seg[node];
  const float lc = cnt[node];

  // ---- batch 8 feat float4 loads (one row per lane, 32B per (lane,ks))
  const float* rp = feat + (size_t)node * DIM + lh * 8;
  float4 fv[4][2];
#pragma unroll
  for (int ks = 0; ks < 4; ++ks) {
    fv[ks][0] = *reinterpret_cast<const float4*>(rp + ks * 32);
    fv[ks][1] = *reinterpret_cast<const float4*>(rp + ks * 32 + 4);
  }

  // ---- batch the q gather (8 float4, L2-resident)
  const float4* q4p = reinterpret_cast<const float4*>(q);
  float4 qv[8];
#pragma unroll
  for (int c = 0; c < 8; ++c) qv[c] = q4p[(size_t)sg * 32 + c * 4 + lh];

  // ---- stage W + w_e into LDS (512 threads: 4 x 8-halfword chunks each;
  //      hw = (i*512+tid)*8 = i*4096 + tid*8  <-- R7 bug was i*8192)
  const uint4* Wt4 = reinterpret_cast<const uint4*>(Wt);
#pragma unroll
  for (int i = 0; i < 4; ++i) {
    int hw = i * 4096 + tid * 8;
    int row = hw >> 7, k0 = hw & 127;
    uint4 wv = Wt4[i * 512 + tid];
    *reinterpret_cast<uint4*>(&sW[row * DIM + (k0 ^ ((row & 7) << 3))]) = wv;
  }
  if (tid < 32)
    reinterpret_cast<float4*>(sWe)[tid] =
        reinterpret_cast<const float4*>(w_e)[tid];

  // ---- cvt feat to bf16 fragments (frees fv)
  bf16x8 af[4];
#pragma unroll
  for (int ks = 0; ks < 4; ++ks) {
    union { bf16x8 v; unsigned short u[8]; } a;
    a.u[0] = bfrne(fv[ks][0].x); a.u[1] = bfrne(fv[ks][0].y);
    a.u[2] = bfrne(fv[ks][0].z); a.u[3] = bfrne(fv[ks][0].w);
    a.u[4] = bfrne(fv[ks][1].x); a.u[5] = bfrne(fv[ks][1].y);
    a.u[6] = bfrne(fv[ks][1].z); a.u[7] = bfrne(fv[ks][1].w);
    af[ks] = a.v;
  }

  __syncthreads();

  // ---- c-loop: 8 keycol-tiles of 16
  float p = 0.0f;
#pragma unroll
  for (int c = 0; c < 8; ++c) {
    const int row = c * 16 + lr;
    bf16x8 wf[4];
#pragma unroll
    for (int ks = 0; ks < 4; ++ks)
      wf[ks] = *reinterpret_cast<const bf16x8*>(
          &sW[row * DIM + ((ks * 32 + lh * 8) ^ ((row & 7) << 3))]);
    float4 we = *reinterpret_cast<const float4*>(&sWe[c * 16 + lh * 4]);

    f32x4 a0 = f32x4{0.f, 0.f, 0.f, 0.f};
#pragma unroll
    for (int ks = 0; ks < 4; ++ks)
      a0 = __builtin_amdgcn_mfma_f32_16x16x32_bf16(wf[ks], af[ks], a0, 0, 0, 0);

    float4 qc = qv[c];
    p += we.x * sigf(a0[0] + qc.x) + we.y * sigf(a0[1] + qc.y) +
         we.z * sigf(a0[2] + qc.z) + we.w * sigf(a0[3] + qc.w);
  }

  // reduce over lh (lanes l, l^16, l^32), lh==0 lanes write
  p += __shfl_xor(p, 16, 64);
  p += __shfl_xor(p, 32, 64);
  if (lh == 0) e[node] = p + __logf(lc);
}

// ---------------------------------------------------------------------------
// Kernel 3: per-graph segment softmax + weighted sum of feat_i.
// ---------------------------------------------------------------------------
__global__ __launch_bounds__(256) void skernel(
    const float* __restrict__ feat, const int* __restrict__ bounds,
    float* __restrict__ e, float* __restrict__ rst) {
  const int b = blockIdx.x;
  const int tid = threadIdx.x;
  const int s0 = bounds[b];
  const int s1 = bounds[b + 1];

  if (s1 <= s0) {
    if (tid < DIM) rst[b * DIM + tid] = 0.0f;
    return;
  }

  __shared__ float red[8];
  __shared__ float part[8 * DIM];
  const int wave = tid >> 6, lane = tid & 63;

  float lm = -3.0e38f;
  for (int i = s0 + tid; i < s1; i += 256) lm = fmaxf(lm, e[i]);
#pragma unroll
  for (int off = 32; off >= 1; off >>= 1) lm = fmaxf(lm, __shfl_xor(lm, off, 64));
  if (lane == 0) red[wave] = lm;
  __syncthreads();
  const float m = fmaxf(fmaxf(red[0], red[1]), fmaxf(red[2], red[3]));

  float ls = 0.0f;
  for (int i = s0 + tid; i < s1; i += 256) {
    float p = __expf(e[i] - m);
    e[i] = p;
    ls += p;
  }
#pragma unroll
  for (int off = 32; off >= 1; off >>= 1) ls += __shfl_xor(ls, off, 64);
  if (lane == 0) red[4 + wave] = ls;
  __syncthreads();
  const float inv = 1.0f / (red[4] + red[5] + red[6] + red[7]);

  const int c = tid & 31;
  const int h = tid >> 5;
  float4 acc = float4{0.f, 0.f, 0.f, 0.f};
  const float4* feat4 = reinterpret_cast<const float4*>(feat);
  for (int n = s0 + h; n < s1; n += 8) {
    float p = e[n];
    float4 f = feat4[n * 32 + c];
    acc.x += p * f.x;
    acc.y += p * f.y;
    acc.z += p * f.z;
    acc.w += p * f.w;
  }
  reinterpret_cast<float4*>(part)[h * 32 + c] = acc;
  __syncthreads();
  if (tid < DIM) {
    float tot = 0.0f;
#pragma unroll
    for (int hh = 0; hh < 8; ++hh) tot += part[hh * DIM + tid];
    rst[b * DIM + tid] = tot * inv;
  }
}

// ---------------------------------------------------------------------------
extern "C" void kernel_launch(void* const* d_in, const int* in_sizes, int n_in,
                              void* d_out, int out_size, void* d_ws,
                              size_t ws_size, hipStream_t stream) {
  const float* feat = (const float*)d_in[0];
  const float* U_feat = (const float*)d_in[1];
  const float* cnt = (const float*)d_in[2];
  const float* W_key = (const float*)d_in[3];
  const float* W_user = (const float*)d_in[4];
  const float* b_user = (const float*)d_in[5];
  const float* W_last = (const float*)d_in[6];
  const float* w_e = (const float*)d_in[7];
  const int* last_nodes = (const int*)d_in[8];
  const int* seg = (const int*)d_in[9];
  float* out = (float*)d_out;

  float* q = (float*)d_ws;                       // 4096*128 f32 (2 MB)
  float* e = q + B_GRAPHS * DIM;                 // 204800 f32 (0.82 MB)
  unsigned short* Wt = (unsigned short*)(e + N_NODES);   // 128*128 bf16 (32 KB)
  int* bounds = (int*)(Wt + DIM * DIM);          // 4097 ints

  qkernel<<<512 + 64 + N_NODES / 128, 128, 0, stream>>>(
      feat, U_feat, W_user, b_user, W_last, last_nodes, W_key, Wt, seg, bounds, q);
  ekernel<<<N_NODES / 128, 512, 0, stream>>>(feat, Wt, w_e, cnt, seg, q, e);
  skernel<<<B_GRAPHS, 256, 0, stream>>>(feat, bounds, e, out);
}

// Round 9
// 63.736 us; speedup vs baseline: 1.2989x; 1.0006x over previous
//
#include <hip/hip_runtime.h>
#include <hip/hip_bf16.h>
#include <math.h>

#define N_NODES 204800
#define B_GRAPHS 4096
#define DIM 128

typedef __attribute__((ext_vector_type(8))) short bf16x8;
typedef __attribute__((ext_vector_type(4))) float f32x4;

__device__ __forceinline__ float sigf(float x) {
    return 1.0f / (1.0f + __expf(-x));
}

// round-to-nearest-even fp32 -> bf16
__device__ __forceinline__ unsigned short bfrne(float x) {
    unsigned u = __float_as_uint(x);
    unsigned r = u + 0x7FFFu + ((u >> 16) & 1u);
    return (unsigned short)(r >> 16);
}

// ---------------------------------------------------------------------------
// Kernel 1, three independent jobs selected by blockIdx.x:
//   [0..512):    q[b] = U_feat[b]@W_user + b_user + feat[last[b]]@W_last
//   [512..576):  Wt_bf16[c][k] = bf16(W_key[k][c])
//   [576..2176): segment bounds scatter: bounds[b] = first node of graph b
// ---------------------------------------------------------------------------
__global__ __launch_bounds__(128) void qkernel(
    const float* __restrict__ feat, const float* __restrict__ U_feat,
    const float* __restrict__ W_user, const float* __restrict__ b_user,
    const float* __restrict__ W_last, const int* __restrict__ last_nodes,
    const float* __restrict__ W_key, unsigned short* __restrict__ Wt,
    const int* __restrict__ seg, int* __restrict__ bounds,
    float* __restrict__ q) {
  if (blockIdx.x >= 576) {
    int n = (blockIdx.x - 576) * 128 + threadIdx.x;
    int sc = seg[n];
    int sp = (n == 0) ? -1 : seg[n - 1];
    for (int b = sp + 1; b <= sc; ++b) bounds[b] = (b == 0) ? 0 : n;
    if (n == N_NODES - 1)
      for (int b = sc + 1; b <= B_GRAPHS; ++b) bounds[b] = N_NODES;
    return;
  }
  if (blockIdx.x >= 512) {
    int b = blockIdx.x - 512;  // 0..63
#pragma unroll
    for (int j = 0; j < 2; ++j) {
      int o = b * 256 + j * 128 + threadIdx.x;  // halfword index in Wt
      int c = o >> 7, k = o & 127;
      Wt[o] = bfrne(W_key[k * DIM + c]);
    }
    return;
  }
  __shared__ float sU[8][DIM];
  __shared__ float sL[8][DIM];
  const int d = threadIdx.x;
  const int g0 = blockIdx.x * 8;
  for (int g = 0; g < 8; ++g) {
    sU[g][d] = U_feat[(g0 + g) * DIM + d];
    int ln = last_nodes[g0 + g];
    sL[g][d] = feat[ln * DIM + d];
  }
  __syncthreads();
  float acc[8];
#pragma unroll
  for (int g = 0; g < 8; ++g) acc[g] = 0.0f;

  for (int kk = 0; kk < 32; ++kk) {
    float wu[4], wl[4];
#pragma unroll
    for (int j = 0; j < 4; ++j) {
      wu[j] = W_user[(kk * 4 + j) * DIM + d];
      wl[j] = W_last[(kk * 4 + j) * DIM + d];
    }
#pragma unroll
    for (int g = 0; g < 8; ++g) {
      float4 u4 = reinterpret_cast<const float4*>(sU[g])[kk];
      float4 l4 = reinterpret_cast<const float4*>(sL[g])[kk];
      acc[g] += u4.x * wu[0] + u4.y * wu[1] + u4.z * wu[2] + u4.w * wu[3];
      acc[g] += l4.x * wl[0] + l4.y * wl[1] + l4.z * wl[2] + l4.w * wl[3];
    }
  }
  float bu = b_user[d];
  for (int g = 0; g < 8; ++g) q[(g0 + g) * DIM + d] = acc[g] + bu;
}

// ---------------------------------------------------------------------------
// Kernel 2: e[n] = sigmoid(q[seg[n]] + (feat[n] @ W_key)) . w_e + log(cnt[n])
// Register-lean variant of R8: peak live state ~85 VGPR so the (512,4)
// 128-VGPR cap cannot spill. q-gather split in two halves of 4 float4:
// half 1 issued pre-barrier, half 2 right after (latency hides under the
// first 4 c-iterations). One 16-node tile per wave; W+w_e staged once per
// block (swizzled, R2-verified). Swapped-operand MFMA:
// D[keycol = c*16 + 4*lh + reg][node = lr].
// ---------------------------------------------------------------------------
__global__ __launch_bounds__(512, 4) void ekernel(
    const float* __restrict__ feat, const unsigned short* __restrict__ Wt,
    const float* __restrict__ w_e, const float* __restrict__ cnt,
    const int* __restrict__ seg, const float* __restrict__ q,
    float* __restrict__ e) {
  __shared__ unsigned short sW[128 * DIM];
  __shared__ float sWe[DIM];
  const int tid = threadIdx.x;
  const int base = blockIdx.x * 128;
  const int l = tid & 63, w = tid >> 6;     // 8 waves
  const int lr = l & 15, lh = l >> 4;
  const int node = base + w * 16 + lr;      // this lane's node (lh-replicated)

  // ---- seg + cnt first (q addresses depend on seg)
  const int sg = seg[node];
  const float lc = cnt[node];

  // ---- batch 8 feat float4 loads (one row per lane, 32B per (lane,ks))
  const float* rp = feat + (size_t)node * DIM + lh * 8;
  float4 fv[4][2];
#pragma unroll
  for (int ks = 0; ks < 4; ++ks) {
    fv[ks][0] = *reinterpret_cast<const float4*>(rp + ks * 32);
    fv[ks][1] = *reinterpret_cast<const float4*>(rp + ks * 32 + 4);
  }

  // ---- stage W + w_e into LDS (512 threads: hw = (i*512+tid)*8)
  const uint4* Wt4 = reinterpret_cast<const uint4*>(Wt);
#pragma unroll
  for (int i = 0; i < 4; ++i) {
    int hw = i * 4096 + tid * 8;
    int row = hw >> 7, k0 = hw & 127;
    uint4 wv = Wt4[i * 512 + tid];
    *reinterpret_cast<uint4*>(&sW[row * DIM + (k0 ^ ((row & 7) << 3))]) = wv;
  }
  if (tid < 32)
    reinterpret_cast<float4*>(sWe)[tid] =
        reinterpret_cast<const float4*>(w_e)[tid];

  // ---- q gather, first half (c = 0..3)
  const float4* q4p = reinterpret_cast<const float4*>(q);
  float4 qv[4];
#pragma unroll
  for (int c = 0; c < 4; ++c) qv[c] = q4p[(size_t)sg * 32 + c * 4 + lh];

  // ---- cvt feat to bf16 fragments (frees fv before qv2 materializes)
  bf16x8 af[4];
#pragma unroll
  for (int ks = 0; ks < 4; ++ks) {
    union { bf16x8 v; unsigned short u[8]; } a;
    a.u[0] = bfrne(fv[ks][0].x); a.u[1] = bfrne(fv[ks][0].y);
    a.u[2] = bfrne(fv[ks][0].z); a.u[3] = bfrne(fv[ks][0].w);
    a.u[4] = bfrne(fv[ks][1].x); a.u[5] = bfrne(fv[ks][1].y);
    a.u[6] = bfrne(fv[ks][1].z); a.u[7] = bfrne(fv[ks][1].w);
    af[ks] = a.v;
  }

  __syncthreads();

  // ---- q gather, second half (latency hides under c=0..3 compute)
  float4 qv2[4];
#pragma unroll
  for (int c = 0; c < 4; ++c) qv2[c] = q4p[(size_t)sg * 32 + 16 + c * 4 + lh];

  // ---- c-loop: 8 keycol-tiles of 16
  float p = 0.0f;
#pragma unroll
  for (int c = 0; c < 8; ++c) {
    const int row = c * 16 + lr;
    bf16x8 wf[4];
#pragma unroll
    for (int ks = 0; ks < 4; ++ks)
      wf[ks] = *reinterpret_cast<const bf16x8*>(
          &sW[row * DIM + ((ks * 32 + lh * 8) ^ ((row & 7) << 3))]);
    float4 we = *reinterpret_cast<const float4*>(&sWe[c * 16 + lh * 4]);

    f32x4 a0 = f32x4{0.f, 0.f, 0.f, 0.f};
#pragma unroll
    for (int ks = 0; ks < 4; ++ks)
      a0 = __builtin_amdgcn_mfma_f32_16x16x32_bf16(wf[ks], af[ks], a0, 0, 0, 0);

    float4 qc = (c < 4) ? qv[c & 3] : qv2[c & 3];
    p += we.x * sigf(a0[0] + qc.x) + we.y * sigf(a0[1] + qc.y) +
         we.z * sigf(a0[2] + qc.z) + we.w * sigf(a0[3] + qc.w);
  }

  // reduce over lh (lanes l, l^16, l^32), lh==0 lanes write
  p += __shfl_xor(p, 16, 64);
  p += __shfl_xor(p, 32, 64);
  if (lh == 0) e[node] = p + __logf(lc);
}

// ---------------------------------------------------------------------------
// Kernel 3: per-graph segment softmax + weighted sum of feat_i.
// ---------------------------------------------------------------------------
__global__ __launch_bounds__(256) void skernel(
    const float* __restrict__ feat, const int* __restrict__ bounds,
    float* __restrict__ e, float* __restrict__ rst) {
  const int b = blockIdx.x;
  const int tid = threadIdx.x;
  const int s0 = bounds[b];
  const int s1 = bounds[b + 1];

  if (s1 <= s0) {
    if (tid < DIM) rst[b * DIM + tid] = 0.0f;
    return;
  }

  __shared__ float red[8];
  __shared__ float part[8 * DIM];
  const int wave = tid >> 6, lane = tid & 63;

  float lm = -3.0e38f;
  for (int i = s0 + tid; i < s1; i += 256) lm = fmaxf(lm, e[i]);
#pragma unroll
  for (int off = 32; off >= 1; off >>= 1) lm = fmaxf(lm, __shfl_xor(lm, off, 64));
  if (lane == 0) red[wave] = lm;
  __syncthreads();
  const float m = fmaxf(fmaxf(red[0], red[1]), fmaxf(red[2], red[3]));

  float ls = 0.0f;
  for (int i = s0 + tid; i < s1; i += 256) {
    float p = __expf(e[i] - m);
    e[i] = p;
    ls += p;
  }
#pragma unroll
  for (int off = 32; off >= 1; off >>= 1) ls += __shfl_xor(ls, off, 64);
  if (lane == 0) red[4 + wave] = ls;
  __syncthreads();
  const float inv = 1.0f / (red[4] + red[5] + red[6] + red[7]);

  const int c = tid & 31;
  const int h = tid >> 5;
  float4 acc = float4{0.f, 0.f, 0.f, 0.f};
  const float4* feat4 = reinterpret_cast<const float4*>(feat);
  for (int n = s0 + h; n < s1; n += 8) {
    float p = e[n];
    float4 f = feat4[n * 32 + c];
    acc.x += p * f.x;
    acc.y += p * f.y;
    acc.z += p * f.z;
    acc.w += p * f.w;
  }
  reinterpret_cast<float4*>(part)[h * 32 + c] = acc;
  __syncthreads();
  if (tid < DIM) {
    float tot = 0.0f;
#pragma unroll
    for (int hh = 0; hh < 8; ++hh) tot += part[hh * DIM + tid];
    rst[b * DIM + tid] = tot * inv;
  }
}

// ---------------------------------------------------------------------------
extern "C" void kernel_launch(void* const* d_in, const int* in_sizes, int n_in,
                              void* d_out, int out_size, void* d_ws,
                              size_t ws_size, hipStream_t stream) {
  const float* feat = (const float*)d_in[0];
  const float* U_feat = (const float*)d_in[1];
  const float* cnt = (const float*)d_in[2];
  const float* W_key = (const float*)d_in[3];
  const float* W_user = (const float*)d_in[4];
  const float* b_user = (const float*)d_in[5];
  const float* W_last = (const float*)d_in[6];
  const float* w_e = (const float*)d_in[7];
  const int* last_nodes = (const int*)d_in[8];
  const int* seg = (const int*)d_in[9];
  float* out = (float*)d_out;

  float* q = (float*)d_ws;                       // 4096*128 f32 (2 MB)
  float* e = q + B_GRAPHS * DIM;                 // 204800 f32 (0.82 MB)
  unsigned short* Wt = (unsigned short*)(e + N_NODES);   // 128*128 bf16 (32 KB)
  int* bounds = (int*)(Wt + DIM * DIM);          // 4097 ints

  qkernel<<<512 + 64 + N_NODES / 128, 128, 0, stream>>>(
      feat, U_feat, W_user, b_user, W_last, last_nodes, W_key, Wt, seg, bounds, q);
  ekernel<<<N_NODES / 128, 512, 0, stream>>>(feat, Wt, w_e, cnt, seg, q, e);
  skernel<<<B_GRAPHS, 256, 0, stream>>>(feat, bounds, e, out);
}